// Round 1
// baseline (1139.031 us; speedup 1.0000x reference)
//
#include <hip/hip_runtime.h>
#include <hip/hip_bf16.h>
#include <math.h>

#define B_ 2
#define T_ 2048
#define C_ 1024
#define H_ 16
#define G_ 4
#define DQK_ 64
#define DV_ 128
#define NQKV 1792   // H*DQK + G*DQK + G*DV = 1024 + 256 + 512

// ---------------------------------------------------------------------------
// Kernel 1: fused QKV projection GEMM.  qkv[B*T, 1792] = x[B*T,1024] @ [Wq|Wk|Wv]
// 128x128 tile, BK=16, 256 threads, 8x8 accum per thread.
// ---------------------------------------------------------------------------
__global__ __launch_bounds__(256) void gemm_qkv(
    const float* __restrict__ x,
    const float* __restrict__ Wq, const float* __restrict__ Wk,
    const float* __restrict__ Wv, float* __restrict__ qkv) {
  __shared__ float As[16][132];   // [k][m], padded
  __shared__ float Bs[16][132];   // [k][n], padded
  const int tid = threadIdx.x;
  const int m0 = blockIdx.y * 128;
  const int n0 = blockIdx.x * 128;

  const float* Wp; int ldw, noff;
  if (n0 < 1024)      { Wp = Wq; ldw = 1024; noff = n0; }
  else if (n0 < 1280) { Wp = Wk; ldw = 256;  noff = n0 - 1024; }
  else                { Wp = Wv; ldw = 512;  noff = n0 - 1280; }

  const int tm = tid >> 4;   // 0..15 -> rows 8*tm .. 8*tm+7
  const int tn = tid & 15;   // cols 4*tn..+3 and 64+4*tn..+3

  float acc[8][8];
#pragma unroll
  for (int i = 0; i < 8; i++)
#pragma unroll
    for (int j = 0; j < 8; j++) acc[i][j] = 0.0f;

  for (int kt = 0; kt < C_ / 16; kt++) {
    __syncthreads();
    // load A tile (128 rows x 16 k) -> As[k][m]
#pragma unroll
    for (int it = 0; it < 2; it++) {
      int fi = tid + it * 256;          // 0..511 float4s
      int r = fi >> 2;                  // 0..127
      int kq = (fi & 3) * 4;            // 0,4,8,12
      float4 av = *(const float4*)&x[(size_t)(m0 + r) * C_ + kt * 16 + kq];
      As[kq + 0][r] = av.x; As[kq + 1][r] = av.y;
      As[kq + 2][r] = av.z; As[kq + 3][r] = av.w;
    }
    // load B tile (16 k x 128 n)
#pragma unroll
    for (int it = 0; it < 2; it++) {
      int fi = tid + it * 256;
      int kk = fi >> 5;                 // 0..15
      int nq = (fi & 31) * 4;           // 0..124
      *(float4*)&Bs[kk][nq] =
          *(const float4*)&Wp[(size_t)(kt * 16 + kk) * ldw + noff + nq];
    }
    __syncthreads();
#pragma unroll
    for (int kk = 0; kk < 16; kk++) {
      float a[8], b[8];
      *(float4*)&a[0] = *(float4*)&As[kk][8 * tm];
      *(float4*)&a[4] = *(float4*)&As[kk][8 * tm + 4];
      *(float4*)&b[0] = *(float4*)&Bs[kk][4 * tn];
      *(float4*)&b[4] = *(float4*)&Bs[kk][64 + 4 * tn];
#pragma unroll
      for (int i = 0; i < 8; i++)
#pragma unroll
        for (int j = 0; j < 8; j++) acc[i][j] += a[i] * b[j];
    }
  }
  // store
#pragma unroll
  for (int i = 0; i < 8; i++) {
    float4 s0 = make_float4(acc[i][0], acc[i][1], acc[i][2], acc[i][3]);
    float4 s1 = make_float4(acc[i][4], acc[i][5], acc[i][6], acc[i][7]);
    size_t row = (size_t)(m0 + 8 * tm + i) * NQKV + n0;
    *(float4*)&qkv[row + 4 * tn] = s0;
    *(float4*)&qkv[row + 64 + 4 * tn] = s1;
  }
}

// ---------------------------------------------------------------------------
// Kernel 2: RoPE + qk-norm + logit-scale epilogue.  One 64-lane wave per
// head-vector.  Writes q -> [B,H,T,64], k -> [B,G,T,64].
// ---------------------------------------------------------------------------
__global__ __launch_bounds__(256) void rope_norm(
    const float* __restrict__ qkv, const float* __restrict__ qknf,
    float* __restrict__ qn, float* __restrict__ kn) {
  const int NQ = B_ * T_ * H_;                     // 65536 q vectors
  int vec = blockIdx.x * 4 + (threadIdx.x >> 6);
  int d = threadIdx.x & 63;

  float val; int t; float* dst; bool isq;
  if (vec < NQ) {
    isq = true;
    int h = vec % H_; int bt = vec / H_;
    t = bt % T_; int b = bt / T_;
    val = qkv[(size_t)bt * NQKV + h * 64 + d];
    dst = qn + (((size_t)(b * H_ + h) * T_ + t) * 64 + d);
  } else {
    isq = false;
    int vk = vec - NQ;
    int g = vk % G_; int bt = vk / G_;
    t = bt % T_; int b = bt / T_;
    val = qkv[(size_t)bt * NQKV + 1024 + g * 64 + d];
    dst = kn + (((size_t)(b * G_ + g) * T_ + t) * 64 + d);
  }
  int i = d & 31;
  float inv = powf(10000.0f, -(float)(2 * i) * (1.0f / 64.0f));
  float ang = (float)t * inv;
  float cs = cosf(ang), sn = sinf(ang);
  float partner = __shfl(val, d ^ 32, 64);
  float r = (d < 32) ? (val * cs - partner * sn) : (val * cs + partner * sn);
  // norm over 64 dims
  float ss = r * r;
#pragma unroll
  for (int off = 32; off; off >>= 1) ss += __shfl_xor(ss, off, 64);
  r *= 1.0f / (sqrtf(ss) + 1e-6f);
  if (isq) r *= qknf[0];   // net logit scale g (sqrt(d) cancels with 1/sqrt(d))
  *dst = r;
}

// ---------------------------------------------------------------------------
// Kernel 3: causal flash attention with sink, head-sum via atomics into y.
// Block = 256 threads, one 64-row Q tile for one (b,h).
// Thread (c = tid&15, rg = tid>>4): rows {rg+16i}, S-cols {c+16jj}, V-dims c*8..+7
// ---------------------------------------------------------------------------
__global__ __launch_bounds__(256) void attn(
    const float* __restrict__ qn, const float* __restrict__ kn,
    const float* __restrict__ qkv, const float* __restrict__ lobo,
    float* __restrict__ y) {
  const int qt = blockIdx.x;   // 0..31
  const int h  = blockIdx.y;   // 0..15
  const int b  = blockIdx.z;   // 0..1
  const int g  = h >> 2;       // repeat_interleave: head h uses group h/4

  __shared__ float Qs[64][68];
  __shared__ float KPs[64][68];   // K tile, then reused as P tile
  __shared__ float Vs[64][128];

  const int tid = threadIdx.x;
  const int c = tid & 15, rg = tid >> 4;

  const float* qbase = qn + ((size_t)(b * H_ + h) * T_ + qt * 64) * 64;
#pragma unroll
  for (int it = 0; it < 4; it++) {
    int l = it * 1024 + tid * 4;
    *(float4*)&Qs[l >> 6][l & 63] = *(const float4*)&qbase[l];
  }

  float o[4][8];
#pragma unroll
  for (int i = 0; i < 4; i++)
#pragma unroll
    for (int u = 0; u < 8; u++) o[i][u] = 0.0f;
  float m_i[4], l_i[4];
  float lb = lobo[h];
#pragma unroll
  for (int i = 0; i < 4; i++) { m_i[i] = lb; l_i[i] = 1.0f; }  // sink term

  const float* kbase0 = kn + ((size_t)(b * G_ + g) * T_) * 64;

  for (int kt = 0; kt <= qt; kt++) {
    __syncthreads();   // previous o-update readers done before overwrite
    const float* kb = kbase0 + (size_t)kt * 64 * 64;
#pragma unroll
    for (int it = 0; it < 4; it++) {
      int l = it * 1024 + tid * 4;
      *(float4*)&KPs[l >> 6][l & 63] = *(const float4*)&kb[l];
    }
#pragma unroll
    for (int it = 0; it < 8; it++) {
      int l = it * 1024 + tid * 4;
      int jr = l >> 7, dv = l & 127;
      *(float4*)&Vs[jr][dv] = *(const float4*)
          &qkv[(size_t)(b * T_ + kt * 64 + jr) * NQKV + 1280 + g * 128 + dv];
    }
    __syncthreads();

    // S = Q K^T  (q already scaled by g, k unit)
    float s[4][4];
#pragma unroll
    for (int i = 0; i < 4; i++)
#pragma unroll
      for (int jj = 0; jj < 4; jj++) s[i][jj] = 0.0f;
#pragma unroll
    for (int d4 = 0; d4 < 16; d4++) {
      float4 a[4], bb[4];
#pragma unroll
      for (int i = 0; i < 4; i++) a[i] = *(float4*)&Qs[rg + 16 * i][d4 * 4];
#pragma unroll
      for (int jj = 0; jj < 4; jj++) bb[jj] = *(float4*)&KPs[c + 16 * jj][d4 * 4];
#pragma unroll
      for (int i = 0; i < 4; i++)
#pragma unroll
        for (int jj = 0; jj < 4; jj++)
          s[i][jj] += a[i].x * bb[jj].x + a[i].y * bb[jj].y +
                      a[i].z * bb[jj].z + a[i].w * bb[jj].w;
    }

    const bool diag = (kt == qt);
    float p[4][4], alpha[4];
#pragma unroll
    for (int i = 0; i < 4; i++) {
      int qi = rg + 16 * i;   // local row
      float mx = -1e30f;
#pragma unroll
      for (int jj = 0; jj < 4; jj++) {
        if (diag && (c + 16 * jj) > qi) s[i][jj] = -1e30f;
        mx = fmaxf(mx, s[i][jj]);
      }
      mx = fmaxf(mx, __shfl_xor(mx, 1, 64));
      mx = fmaxf(mx, __shfl_xor(mx, 2, 64));
      mx = fmaxf(mx, __shfl_xor(mx, 4, 64));
      mx = fmaxf(mx, __shfl_xor(mx, 8, 64));
      float mnew = fmaxf(m_i[i], mx);
      alpha[i] = expf(m_i[i] - mnew);
      float rs = 0.0f;
#pragma unroll
      for (int jj = 0; jj < 4; jj++) {
        float pv = expf(s[i][jj] - mnew);
        p[i][jj] = pv; rs += pv;
      }
      rs += __shfl_xor(rs, 1, 64);
      rs += __shfl_xor(rs, 2, 64);
      rs += __shfl_xor(rs, 4, 64);
      rs += __shfl_xor(rs, 8, 64);
      l_i[i] = l_i[i] * alpha[i] + rs;
      m_i[i] = mnew;
#pragma unroll
      for (int u = 0; u < 8; u++) o[i][u] *= alpha[i];
    }
    __syncthreads();   // all S reads of KPs done
#pragma unroll
    for (int i = 0; i < 4; i++)
#pragma unroll
      for (int jj = 0; jj < 4; jj++)
        KPs[rg + 16 * i][c + 16 * jj] = p[i][jj];
    __syncthreads();

    // O += P V
#pragma unroll 4
    for (int j = 0; j < 64; j++) {
      float4 v0 = *(float4*)&Vs[j][c * 8];
      float4 v1 = *(float4*)&Vs[j][c * 8 + 4];
#pragma unroll
      for (int i = 0; i < 4; i++) {
        float pv = KPs[rg + 16 * i][j];
        o[i][0] += pv * v0.x; o[i][1] += pv * v0.y;
        o[i][2] += pv * v0.z; o[i][3] += pv * v0.w;
        o[i][4] += pv * v1.x; o[i][5] += pv * v1.y;
        o[i][6] += pv * v1.z; o[i][7] += pv * v1.w;
      }
    }
  }

#pragma unroll
  for (int i = 0; i < 4; i++) {
    float invl = 1.0f / l_i[i];
    size_t row = (size_t)b * T_ + qt * 64 + rg + 16 * i;
#pragma unroll
    for (int u = 0; u < 8; u++)
      atomicAdd(&y[row * 128 + c * 8 + u], o[i][u] * invl);
  }
}

// ---------------------------------------------------------------------------
// Kernel 4: out = y[B*T,128] @ Wproj[128,1024].  4 rows per block.
// ---------------------------------------------------------------------------
__global__ __launch_bounds__(256) void out_proj(
    const float* __restrict__ y, const float* __restrict__ Wproj,
    float* __restrict__ out) {
  __shared__ float ylds[4][128];
  const int m0 = blockIdx.x * 4;
  const int tid = threadIdx.x;
  *(float2*)&((float*)ylds)[tid * 2] = *(const float2*)&y[(size_t)m0 * 128 + tid * 2];
  __syncthreads();
  float acc[4][4];
#pragma unroll
  for (int i = 0; i < 4; i++)
#pragma unroll
    for (int j = 0; j < 4; j++) acc[i][j] = 0.0f;
  for (int k = 0; k < 128; k++) {
    float w[4];
#pragma unroll
    for (int j = 0; j < 4; j++) w[j] = Wproj[(size_t)k * 1024 + tid + 256 * j];
#pragma unroll
    for (int i = 0; i < 4; i++) {
      float yv = ylds[i][k];
#pragma unroll
      for (int j = 0; j < 4; j++) acc[i][j] += yv * w[j];
    }
  }
#pragma unroll
  for (int i = 0; i < 4; i++)
#pragma unroll
    for (int j = 0; j < 4; j++)
      out[(size_t)(m0 + i) * 1024 + tid + 256 * j] = acc[i][j];
}

// ---------------------------------------------------------------------------
extern "C" void kernel_launch(void* const* d_in, const int* in_sizes, int n_in,
                              void* d_out, int out_size, void* d_ws, size_t ws_size,
                              hipStream_t stream) {
  const float* x     = (const float*)d_in[0];
  // d_in[1] = iter_num (unused)
  const float* Wq    = (const float*)d_in[2];
  const float* Wk    = (const float*)d_in[3];
  const float* Wv    = (const float*)d_in[4];
  const float* Wproj = (const float*)d_in[5];
  const float* lobo  = (const float*)d_in[6];
  const float* qknf  = (const float*)d_in[7];
  float* out = (float*)d_out;

  float* ws = (float*)d_ws;
  float* qkv = ws;                                   // B*T*1792   = 7,340,032
  float* qn  = qkv + (size_t)B_ * T_ * NQKV;         // B*H*T*64   = 4,194,304
  float* kn  = qn  + (size_t)B_ * H_ * T_ * 64;      // B*G*T*64   = 1,048,576
  float* y   = kn  + (size_t)B_ * G_ * T_ * 64;      // B*T*128    =   524,288

  dim3 gg(NQKV / 128, (B_ * T_) / 128);
  gemm_qkv<<<gg, 256, 0, stream>>>(x, Wq, Wk, Wv, qkv);

  int nvec = B_ * T_ * H_ + B_ * T_ * G_;            // 81920
  rope_norm<<<nvec / 4, 256, 0, stream>>>(qkv, qknf, qn, kn);

  hipMemsetAsync(y, 0, (size_t)B_ * T_ * 128 * sizeof(float), stream);

  dim3 ga(T_ / 64, H_, B_);
  attn<<<ga, 256, 0, stream>>>(qn, kn, qkv, lobo, y);

  out_proj<<<(B_ * T_) / 4, 256, 0, stream>>>(y, Wproj, out);
}

// Round 2
// 507.124 us; speedup vs baseline: 2.2461x; 2.2461x over previous
//
#include <hip/hip_runtime.h>
#include <hip/hip_bf16.h>
#include <math.h>

#define B_ 2
#define T_ 2048
#define C_ 1024
#define H_ 16
#define G_ 4
#define DQK_ 64
#define DV_ 128
#define NQKV 1792   // H*DQK + G*DQK + G*DV

typedef __attribute__((ext_vector_type(8))) short short8;
typedef __attribute__((ext_vector_type(4))) float f32x4;
typedef unsigned short ushort_t;

__device__ inline ushort_t f2bf(float f) {
  union { float f; unsigned int u; } v; v.f = f;
  unsigned int r = (v.u + 0x7FFFu + ((v.u >> 16) & 1u)) >> 16;  // RNE
  return (ushort_t)r;
}

// ---------------------------------------------------------------------------
// Kernel 1: fused QKV projection GEMM (fp32, unchanged this round).
// ---------------------------------------------------------------------------
__global__ __launch_bounds__(256) void gemm_qkv(
    const float* __restrict__ x,
    const float* __restrict__ Wq, const float* __restrict__ Wk,
    const float* __restrict__ Wv, float* __restrict__ qkv) {
  __shared__ float As[16][132];
  __shared__ float Bs[16][132];
  const int tid = threadIdx.x;
  const int m0 = blockIdx.y * 128;
  const int n0 = blockIdx.x * 128;

  const float* Wp; int ldw, noff;
  if (n0 < 1024)      { Wp = Wq; ldw = 1024; noff = n0; }
  else if (n0 < 1280) { Wp = Wk; ldw = 256;  noff = n0 - 1024; }
  else                { Wp = Wv; ldw = 512;  noff = n0 - 1280; }

  const int tm = tid >> 4;
  const int tn = tid & 15;

  float acc[8][8];
#pragma unroll
  for (int i = 0; i < 8; i++)
#pragma unroll
    for (int j = 0; j < 8; j++) acc[i][j] = 0.0f;

  for (int kt = 0; kt < C_ / 16; kt++) {
    __syncthreads();
#pragma unroll
    for (int it = 0; it < 2; it++) {
      int fi = tid + it * 256;
      int r = fi >> 2;
      int kq = (fi & 3) * 4;
      float4 av = *(const float4*)&x[(size_t)(m0 + r) * C_ + kt * 16 + kq];
      As[kq + 0][r] = av.x; As[kq + 1][r] = av.y;
      As[kq + 2][r] = av.z; As[kq + 3][r] = av.w;
    }
#pragma unroll
    for (int it = 0; it < 2; it++) {
      int fi = tid + it * 256;
      int kk = fi >> 5;
      int nq = (fi & 31) * 4;
      *(float4*)&Bs[kk][nq] =
          *(const float4*)&Wp[(size_t)(kt * 16 + kk) * ldw + noff + nq];
    }
    __syncthreads();
#pragma unroll
    for (int kk = 0; kk < 16; kk++) {
      float a[8], b[8];
      *(float4*)&a[0] = *(float4*)&As[kk][8 * tm];
      *(float4*)&a[4] = *(float4*)&As[kk][8 * tm + 4];
      *(float4*)&b[0] = *(float4*)&Bs[kk][4 * tn];
      *(float4*)&b[4] = *(float4*)&Bs[kk][64 + 4 * tn];
#pragma unroll
      for (int i = 0; i < 8; i++)
#pragma unroll
        for (int j = 0; j < 8; j++) acc[i][j] += a[i] * b[j];
    }
  }
#pragma unroll
  for (int i = 0; i < 8; i++) {
    float4 s0 = make_float4(acc[i][0], acc[i][1], acc[i][2], acc[i][3]);
    float4 s1 = make_float4(acc[i][4], acc[i][5], acc[i][6], acc[i][7]);
    size_t row = (size_t)(m0 + 8 * tm + i) * NQKV + n0;
    *(float4*)&qkv[row + 4 * tn] = s0;
    *(float4*)&qkv[row + 64 + 4 * tn] = s1;
  }
}

// ---------------------------------------------------------------------------
// Kernel 2: RoPE + qk-norm. Writes UNIT-norm bf16 q,k (logit scale applied
// later in fp32 inside attention).
// ---------------------------------------------------------------------------
__global__ __launch_bounds__(256) void rope_norm(
    const float* __restrict__ qkv,
    ushort_t* __restrict__ qn, ushort_t* __restrict__ kn) {
  const int NQ = B_ * T_ * H_;
  int vec = blockIdx.x * 4 + (threadIdx.x >> 6);
  int d = threadIdx.x & 63;

  float val; int t; ushort_t* dst;
  if (vec < NQ) {
    int h = vec % H_; int bt = vec / H_;
    t = bt % T_; int b = bt / T_;
    val = qkv[(size_t)bt * NQKV + h * 64 + d];
    dst = qn + (((size_t)(b * H_ + h) * T_ + t) * 64 + d);
  } else {
    int vk = vec - NQ;
    int g = vk % G_; int bt = vk / G_;
    t = bt % T_; int b = bt / T_;
    val = qkv[(size_t)bt * NQKV + 1024 + g * 64 + d];
    dst = kn + (((size_t)(b * G_ + g) * T_ + t) * 64 + d);
  }
  int i = d & 31;
  float inv = powf(10000.0f, -(float)(2 * i) * (1.0f / 64.0f));
  float ang = (float)t * inv;
  float cs = cosf(ang), sn = sinf(ang);
  float partner = __shfl(val, d ^ 32, 64);
  float r = (d < 32) ? (val * cs - partner * sn) : (val * cs + partner * sn);
  float ss = r * r;
#pragma unroll
  for (int off = 32; off; off >>= 1) ss += __shfl_xor(ss, off, 64);
  r *= 1.0f / (sqrtf(ss) + 1e-6f);
  *dst = f2bf(r);
}

// ---------------------------------------------------------------------------
// Kernel 2b: V transpose + bf16 cast.  vt[b][g][dv][t] = bf16(v[b][t][g][dv])
// Grid: (T/64, B*G). LDS tile 64 t x 128 dv.
// ---------------------------------------------------------------------------
__global__ __launch_bounds__(256) void vtrans(
    const float* __restrict__ qkv, ushort_t* __restrict__ vt) {
  __shared__ ushort_t tile[128 * 72];
  const int bg = blockIdx.y;
  const int b = bg >> 2, g = bg & 3;
  const int t0 = blockIdx.x * 64;
  const int tid = threadIdx.x;
#pragma unroll
  for (int it = 0; it < 8; it++) {
    int fi = it * 256 + tid;            // 2048 float4s
    int tl = fi >> 5;                   // 0..63
    int dq = (fi & 31) * 4;             // 0..124
    float4 v = *(const float4*)
        &qkv[(size_t)(b * T_ + t0 + tl) * NQKV + 1280 + g * 128 + dq];
    tile[(dq + 0) * 72 + tl] = f2bf(v.x);
    tile[(dq + 1) * 72 + tl] = f2bf(v.y);
    tile[(dq + 2) * 72 + tl] = f2bf(v.z);
    tile[(dq + 3) * 72 + tl] = f2bf(v.w);
  }
  __syncthreads();
  int dv = tid >> 1, seg = tid & 1;
  ushort_t* dst = vt + ((size_t)(b * G_ + g) * 128 + dv) * T_ + t0 + seg * 32;
  const ushort_t* src = &tile[dv * 72 + seg * 32];
#pragma unroll
  for (int u = 0; u < 4; u++)
    *(float4*)&dst[u * 8] = *(const float4*)&src[u * 8];
}

// ---------------------------------------------------------------------------
// Kernel 3: bf16-MFMA causal flash attention with sink; head-sum via atomics.
// Block = 256 (4 waves); block owns 64 Q rows of one (b,h); wave owns 16 rows.
// ---------------------------------------------------------------------------
__global__ __launch_bounds__(256) void attn(
    const ushort_t* __restrict__ qn, const ushort_t* __restrict__ kn,
    const ushort_t* __restrict__ vt, const float* __restrict__ lobo,
    const float* __restrict__ qknf, float* __restrict__ y) {
  const int qt = blockIdx.x;
  const int h  = blockIdx.y;
  const int b  = blockIdx.z;
  const int g  = h >> 2;

  __shared__ short Qs[64 * 72];
  __shared__ short Ks[64 * 72];
  __shared__ short Vs[128 * 72];
  __shared__ short Ps[64 * 72];

  const int tid = threadIdx.x;
  const int wave = tid >> 6, lane = tid & 63;
  const int quad = lane >> 4, l16 = lane & 15;

  // stage Q tile (64 x 64 bf16)
  {
    const ushort_t* qb = qn + ((size_t)(b * H_ + h) * T_ + qt * 64) * 64;
    int r = tid >> 2, part = tid & 3;
    *(float4*)&Qs[r * 72 + part * 16] = *(const float4*)&qb[r * 64 + part * 16];
    *(float4*)&Qs[r * 72 + part * 16 + 8] =
        *(const float4*)&qb[r * 64 + part * 16 + 8];
  }

  f32x4 o[8];
#pragma unroll
  for (int nt = 0; nt < 8; nt++) o[nt] = (f32x4){0.f, 0.f, 0.f, 0.f};
  float m_i[4], l_i[4];
  const float lb = lobo[h];
  const float gsc = qknf[0];
#pragma unroll
  for (int r = 0; r < 4; r++) { m_i[r] = lb; l_i[r] = 1.0f; }  // sink

  const ushort_t* kbase = kn + ((size_t)(b * G_ + g) * T_) * 64;
  const ushort_t* vbase = vt + ((size_t)(b * G_ + g) * 128) * T_;

  for (int kt = 0; kt <= qt; kt++) {
    __syncthreads();
    // stage K (64 x 64)
    {
      const ushort_t* kb = kbase + (size_t)kt * 64 * 64;
      int r = tid >> 2, part = tid & 3;
      *(float4*)&Ks[r * 72 + part * 16] = *(const float4*)&kb[r * 64 + part * 16];
      *(float4*)&Ks[r * 72 + part * 16 + 8] =
          *(const float4*)&kb[r * 64 + part * 16 + 8];
    }
    // stage V^T tile (128 dv x 64 keys)
    {
      int dv = tid >> 1, seg = tid & 1;
      const ushort_t* vb = vbase + (size_t)dv * T_ + kt * 64 + seg * 32;
      short* dst = &Vs[dv * 72 + seg * 32];
#pragma unroll
      for (int u = 0; u < 4; u++)
        *(float4*)&dst[u * 8] = *(const float4*)&vb[u * 8];
    }
    __syncthreads();

    // S = Q K^T  (16 rows x 64 keys per wave)
    f32x4 s[4];
#pragma unroll
    for (int nt = 0; nt < 4; nt++) s[nt] = (f32x4){0.f, 0.f, 0.f, 0.f};
#pragma unroll
    for (int ks = 0; ks < 2; ks++) {
      short8 aq = *(const short8*)&Qs[(wave * 16 + l16) * 72 + ks * 32 + quad * 8];
#pragma unroll
      for (int nt = 0; nt < 4; nt++) {
        short8 bk = *(const short8*)&Ks[(nt * 16 + l16) * 72 + ks * 32 + quad * 8];
        s[nt] = __builtin_amdgcn_mfma_f32_16x16x32_bf16(aq, bk, s[nt], 0, 0, 0);
      }
    }

    const bool diag = (kt == qt);
    float p[4][4], alpha[4];
#pragma unroll
    for (int r = 0; r < 4; r++) {
      int row = wave * 16 + quad * 4 + r;   // local query row (0..63)
      float sv[4];
#pragma unroll
      for (int nt = 0; nt < 4; nt++) {
        sv[nt] = s[nt][r] * gsc;
        if (diag && (nt * 16 + l16) > row) sv[nt] = -1e30f;
      }
      float mx = fmaxf(fmaxf(sv[0], sv[1]), fmaxf(sv[2], sv[3]));
      mx = fmaxf(mx, __shfl_xor(mx, 1, 64));
      mx = fmaxf(mx, __shfl_xor(mx, 2, 64));
      mx = fmaxf(mx, __shfl_xor(mx, 4, 64));
      mx = fmaxf(mx, __shfl_xor(mx, 8, 64));
      float mnew = fmaxf(m_i[r], mx);
      alpha[r] = __expf(m_i[r] - mnew);
      float rs = 0.f;
#pragma unroll
      for (int nt = 0; nt < 4; nt++) {
        float pv = __expf(sv[nt] - mnew);
        p[nt][r] = pv; rs += pv;
      }
      rs += __shfl_xor(rs, 1, 64);
      rs += __shfl_xor(rs, 2, 64);
      rs += __shfl_xor(rs, 4, 64);
      rs += __shfl_xor(rs, 8, 64);
      l_i[r] = l_i[r] * alpha[r] + rs;
      m_i[r] = mnew;
#pragma unroll
      for (int nv = 0; nv < 8; nv++) o[nv][r] *= alpha[r];
    }

    // P -> LDS (per-wave private region; no barrier needed)
#pragma unroll
    for (int nt = 0; nt < 4; nt++)
#pragma unroll
      for (int r = 0; r < 4; r++)
        Ps[(wave * 16 + quad * 4 + r) * 72 + nt * 16 + l16] =
            (short)f2bf(p[nt][r]);

    // O += P V
#pragma unroll
    for (int ks = 0; ks < 2; ks++) {
      short8 ap = *(const short8*)&Ps[(wave * 16 + l16) * 72 + ks * 32 + quad * 8];
#pragma unroll
      for (int nv = 0; nv < 8; nv++) {
        short8 bv = *(const short8*)&Vs[(nv * 16 + l16) * 72 + ks * 32 + quad * 8];
        o[nv] = __builtin_amdgcn_mfma_f32_16x16x32_bf16(ap, bv, o[nv], 0, 0, 0);
      }
    }
  }

  // epilogue: head-sum via atomics
#pragma unroll
  for (int r = 0; r < 4; r++) {
    float invl = 1.0f / l_i[r];
    size_t row = (size_t)b * T_ + qt * 64 + wave * 16 + quad * 4 + r;
#pragma unroll
    for (int nv = 0; nv < 8; nv++)
      atomicAdd(&y[row * 128 + nv * 16 + l16], o[nv][r] * invl);
  }
}

// ---------------------------------------------------------------------------
// Kernel 4: out = y[B*T,128] @ Wproj[128,1024]  (fp32, unchanged).
// ---------------------------------------------------------------------------
__global__ __launch_bounds__(256) void out_proj(
    const float* __restrict__ y, const float* __restrict__ Wproj,
    float* __restrict__ out) {
  __shared__ float ylds[4][128];
  const int m0 = blockIdx.x * 4;
  const int tid = threadIdx.x;
  *(float2*)&((float*)ylds)[tid * 2] = *(const float2*)&y[(size_t)m0 * 128 + tid * 2];
  __syncthreads();
  float acc[4][4];
#pragma unroll
  for (int i = 0; i < 4; i++)
#pragma unroll
    for (int j = 0; j < 4; j++) acc[i][j] = 0.0f;
  for (int k = 0; k < 128; k++) {
    float w[4];
#pragma unroll
    for (int j = 0; j < 4; j++) w[j] = Wproj[(size_t)k * 1024 + tid + 256 * j];
#pragma unroll
    for (int i = 0; i < 4; i++) {
      float yv = ylds[i][k];
#pragma unroll
      for (int j = 0; j < 4; j++) acc[i][j] += yv * w[j];
    }
  }
#pragma unroll
  for (int i = 0; i < 4; i++)
#pragma unroll
    for (int j = 0; j < 4; j++)
      out[(size_t)(m0 + i) * 1024 + tid + 256 * j] = acc[i][j];
}

// ---------------------------------------------------------------------------
extern "C" void kernel_launch(void* const* d_in, const int* in_sizes, int n_in,
                              void* d_out, int out_size, void* d_ws, size_t ws_size,
                              hipStream_t stream) {
  const float* x     = (const float*)d_in[0];
  const float* Wq    = (const float*)d_in[2];
  const float* Wk    = (const float*)d_in[3];
  const float* Wv    = (const float*)d_in[4];
  const float* Wproj = (const float*)d_in[5];
  const float* lobo  = (const float*)d_in[6];
  const float* qknf  = (const float*)d_in[7];
  float* out = (float*)d_out;

  float* qkv = (float*)d_ws;                               // 7,340,032 f32
  ushort_t* qn = (ushort_t*)(qkv + (size_t)B_ * T_ * NQKV);  // 4,194,304 bf16
  ushort_t* kn = qn + (size_t)B_ * H_ * T_ * 64;             // 1,048,576 bf16
  ushort_t* vt = kn + (size_t)B_ * G_ * T_ * 64;             // 2,097,152 bf16
  float* y = (float*)(vt + (size_t)B_ * G_ * 128 * T_);      //   524,288 f32

  dim3 gg(NQKV / 128, (B_ * T_) / 128);
  gemm_qkv<<<gg, 256, 0, stream>>>(x, Wq, Wk, Wv, qkv);

  int nvec = B_ * T_ * H_ + B_ * T_ * G_;   // 81920
  rope_norm<<<nvec / 4, 256, 0, stream>>>(qkv, qn, kn);

  dim3 gv(T_ / 64, B_ * G_);
  vtrans<<<gv, 256, 0, stream>>>(qkv, vt);

  hipMemsetAsync(y, 0, (size_t)B_ * T_ * 128 * sizeof(float), stream);

  dim3 ga(T_ / 64, H_, B_);
  attn<<<ga, 256, 0, stream>>>(qn, kn, vt, lobo, qknf, y);

  out_proj<<<(B_ * T_) / 4, 256, 0, stream>>>(y, Wproj, out);
}

// Round 3
// 406.298 us; speedup vs baseline: 2.8034x; 1.2482x over previous
//
#include <hip/hip_runtime.h>
#include <hip/hip_bf16.h>
#include <math.h>

#define B_ 2
#define T_ 2048
#define C_ 1024
#define H_ 16
#define G_ 4
#define DQK_ 64
#define DV_ 128
#define NQKV 1792   // H*DQK + G*DQK + G*DV
#define KSPLIT 3072 // [x_hi | x_lo | x_hi] · [w_hi ; w_hi ; w_lo]

typedef __attribute__((ext_vector_type(8))) short short8;
typedef __attribute__((ext_vector_type(4))) short short4v;
typedef __attribute__((ext_vector_type(4))) float f32x4;
typedef unsigned short ushort_t;

__device__ inline ushort_t f2bf(float f) {
  union { float f; unsigned int u; } v; v.f = f;
  unsigned int r = (v.u + 0x7FFFu + ((v.u >> 16) & 1u)) >> 16;  // RNE
  return (ushort_t)r;
}
__device__ inline float bf2f(ushort_t h) {
  union { unsigned int u; float f; } v; v.u = ((unsigned int)h) << 16;
  return v.f;
}

#define GLD_LDS16(g, l)                                              \
  __builtin_amdgcn_global_load_lds(                                  \
      (const __attribute__((address_space(1))) void*)(g),            \
      (__attribute__((address_space(3))) void*)(l), 16, 0, 0)

// ---------------------------------------------------------------------------
// Kernel 0a: split-cast x -> xb[4096][3072] bf16 = [x_hi | x_lo | x_hi]
// ---------------------------------------------------------------------------
__global__ __launch_bounds__(256) void cast_x(
    const float* __restrict__ x, ushort_t* __restrict__ xb) {
  int idx = blockIdx.x * 256 + threadIdx.x;      // 1,048,576 float4s
  int m = idx >> 8;
  int kq = (idx & 255) * 4;
  float4 v = *(const float4*)&x[(size_t)m * 1024 + kq];
  ushort_t h[4], l[4];
  float f[4] = {v.x, v.y, v.z, v.w};
#pragma unroll
  for (int c = 0; c < 4; c++) {
    h[c] = f2bf(f[c]);
    l[c] = f2bf(f[c] - bf2f(h[c]));
  }
  short4v hv = {(short)h[0], (short)h[1], (short)h[2], (short)h[3]};
  short4v lv = {(short)l[0], (short)l[1], (short)l[2], (short)l[3]};
  ushort_t* row = xb + (size_t)m * KSPLIT;
  *(short4v*)&row[kq] = hv;
  *(short4v*)&row[1024 + kq] = lv;
  *(short4v*)&row[2048 + kq] = hv;
}

// ---------------------------------------------------------------------------
// Kernel 0b: transpose+split-cast W -> wt[1792][3072] bf16,
// wt[n][k] = w_hi[k][n] (k<1024), w_hi[k-1024][n] (<2048), w_lo[k-2048][n].
// Grid (28 n-tiles, 16 k-tiles), 64x64 tiles.
// ---------------------------------------------------------------------------
__global__ __launch_bounds__(256) void cast_w(
    const float* __restrict__ Wq, const float* __restrict__ Wk,
    const float* __restrict__ Wv, ushort_t* __restrict__ wt) {
  __shared__ float tile[64][65];   // [n][k]
  const int n0 = blockIdx.x * 64;
  const int k0 = blockIdx.y * 64;
  const int tid = threadIdx.x;

  const float* Wp; int ldw, noff;
  if (n0 < 1024)      { Wp = Wq; ldw = 1024; noff = n0; }
  else if (n0 < 1280) { Wp = Wk; ldw = 256;  noff = n0 - 1024; }
  else                { Wp = Wv; ldw = 512;  noff = n0 - 1280; }

#pragma unroll
  for (int it = 0; it < 4; it++) {
    int fi = it * 256 + tid;       // 1024 float4s
    int kk = fi >> 4;              // 0..63
    int nc = (fi & 15) * 4;        // 0..60
    float4 v = *(const float4*)&Wp[(size_t)(k0 + kk) * ldw + noff + nc];
    tile[nc + 0][kk] = v.x; tile[nc + 1][kk] = v.y;
    tile[nc + 2][kk] = v.z; tile[nc + 3][kk] = v.w;
  }
  __syncthreads();
  int nn = tid >> 2, seg = tid & 3;   // 16 k per thread
  ushort_t hb[16], lb[16];
#pragma unroll
  for (int u = 0; u < 16; u++) {
    float f = tile[nn][seg * 16 + u];
    hb[u] = f2bf(f);
    lb[u] = f2bf(f - bf2f(hb[u]));
  }
  ushort_t* row = wt + (size_t)(n0 + nn) * KSPLIT + k0 + seg * 16;
  *(float4*)&row[0] = *(float4*)&hb[0];
  *(float4*)&row[8] = *(float4*)&hb[8];
  *(float4*)&row[1024] = *(float4*)&hb[0];
  *(float4*)&row[1024 + 8] = *(float4*)&hb[8];
  *(float4*)&row[2048] = *(float4*)&lb[0];
  *(float4*)&row[2048 + 8] = *(float4*)&lb[8];
}

// ---------------------------------------------------------------------------
// Kernel 1: bf16-MFMA QKV GEMM.  qkv[4096][1792] = xb[4096][3072] @ wt^T
// 128x128 tile, BK=32, 256 threads, m97 structure (global_load_lds w=16).
// ---------------------------------------------------------------------------
__global__ __launch_bounds__(256) void gemm_qkv_mfma(
    const ushort_t* __restrict__ xb, const ushort_t* __restrict__ wt,
    float* __restrict__ qkv) {
  __shared__ ushort_t At[128 * 32];
  __shared__ ushort_t Bt[128 * 32];
  const int tid = threadIdx.x;
  const int wave = tid >> 6, lane = tid & 63;
  const int quad = lane >> 4, l16 = lane & 15;
  const int m0 = blockIdx.y * 128, n0 = blockIdx.x * 128;
  const int wm = (wave & 1) * 64, wn = (wave >> 1) * 64;

  f32x4 acc[4][4];
#pragma unroll
  for (int i = 0; i < 4; i++)
#pragma unroll
    for (int j = 0; j < 4; j++) acc[i][j] = (f32x4){0.f, 0.f, 0.f, 0.f};

  const int rA = wave * 32 + (lane >> 2);     // staging row (issue 0)
  const int cA = (lane & 3) * 8;              // staging k-offset (elements)
  const ushort_t* gA = xb + (size_t)(m0 + rA) * KSPLIT + cA;
  const ushort_t* gB = wt + (size_t)(n0 + rA) * KSPLIT + cA;
  ushort_t* lA0 = At + (size_t)(wave * 32) * 32;
  ushort_t* lA1 = At + (size_t)(wave * 32 + 16) * 32;
  ushort_t* lB0 = Bt + (size_t)(wave * 32) * 32;
  ushort_t* lB1 = Bt + (size_t)(wave * 32 + 16) * 32;

  for (int kt = 0; kt < KSPLIT / 32; kt++) {
    __syncthreads();
    const ushort_t* a = gA + kt * 32;
    const ushort_t* b = gB + kt * 32;
    GLD_LDS16(a, lA0);
    GLD_LDS16(a + 16 * KSPLIT, lA1);
    GLD_LDS16(b, lB0);
    GLD_LDS16(b + 16 * KSPLIT, lB1);
    __syncthreads();

    short8 af[4], bf[4];
#pragma unroll
    for (int i = 0; i < 4; i++)
      af[i] = *(const short8*)&At[(wm + 16 * i + l16) * 32 + quad * 8];
#pragma unroll
    for (int j = 0; j < 4; j++)
      bf[j] = *(const short8*)&Bt[(wn + 16 * j + l16) * 32 + quad * 8];
#pragma unroll
    for (int i = 0; i < 4; i++)
#pragma unroll
      for (int j = 0; j < 4; j++)
        acc[i][j] = __builtin_amdgcn_mfma_f32_16x16x32_bf16(
            af[i], bf[j], acc[i][j], 0, 0, 0);
  }

#pragma unroll
  for (int i = 0; i < 4; i++) {
    int m = m0 + wm + 16 * i + quad * 4;
#pragma unroll
    for (int j = 0; j < 4; j++) {
      int n = n0 + wn + 16 * j + l16;
#pragma unroll
      for (int r = 0; r < 4; r++)
        qkv[(size_t)(m + r) * NQKV + n] = acc[i][j][r];
    }
  }
}

// ---------------------------------------------------------------------------
// Kernel 2: RoPE + qk-norm -> unit-norm bf16 q,k.
// ---------------------------------------------------------------------------
__global__ __launch_bounds__(256) void rope_norm(
    const float* __restrict__ qkv,
    ushort_t* __restrict__ qn, ushort_t* __restrict__ kn) {
  const int NQ = B_ * T_ * H_;
  int vec = blockIdx.x * 4 + (threadIdx.x >> 6);
  int d = threadIdx.x & 63;

  float val; int t; ushort_t* dst;
  if (vec < NQ) {
    int h = vec % H_; int bt = vec / H_;
    t = bt % T_; int b = bt / T_;
    val = qkv[(size_t)bt * NQKV + h * 64 + d];
    dst = qn + (((size_t)(b * H_ + h) * T_ + t) * 64 + d);
  } else {
    int vk = vec - NQ;
    int g = vk % G_; int bt = vk / G_;
    t = bt % T_; int b = bt / T_;
    val = qkv[(size_t)bt * NQKV + 1024 + g * 64 + d];
    dst = kn + (((size_t)(b * G_ + g) * T_ + t) * 64 + d);
  }
  int i = d & 31;
  float inv = powf(10000.0f, -(float)(2 * i) * (1.0f / 64.0f));
  float ang = (float)t * inv;
  float cs = cosf(ang), sn = sinf(ang);
  float partner = __shfl(val, d ^ 32, 64);
  float r = (d < 32) ? (val * cs - partner * sn) : (val * cs + partner * sn);
  float ss = r * r;
#pragma unroll
  for (int off = 32; off; off >>= 1) ss += __shfl_xor(ss, off, 64);
  r *= 1.0f / (sqrtf(ss) + 1e-6f);
  *dst = f2bf(r);
}

// ---------------------------------------------------------------------------
// Kernel 2b: V transpose + bf16 cast.  vt[b][g][dv][t]
// ---------------------------------------------------------------------------
__global__ __launch_bounds__(256) void vtrans(
    const float* __restrict__ qkv, ushort_t* __restrict__ vt) {
  __shared__ ushort_t tile[128 * 72];
  const int bg = blockIdx.y;
  const int b = bg >> 2, g = bg & 3;
  const int t0 = blockIdx.x * 64;
  const int tid = threadIdx.x;
#pragma unroll
  for (int it = 0; it < 8; it++) {
    int fi = it * 256 + tid;
    int tl = fi >> 5;
    int dq = (fi & 31) * 4;
    float4 v = *(const float4*)
        &qkv[(size_t)(b * T_ + t0 + tl) * NQKV + 1280 + g * 128 + dq];
    tile[(dq + 0) * 72 + tl] = f2bf(v.x);
    tile[(dq + 1) * 72 + tl] = f2bf(v.y);
    tile[(dq + 2) * 72 + tl] = f2bf(v.z);
    tile[(dq + 3) * 72 + tl] = f2bf(v.w);
  }
  __syncthreads();
  int dv = tid >> 1, seg = tid & 1;
  ushort_t* dst = vt + ((size_t)(b * G_ + g) * 128 + dv) * T_ + t0 + seg * 32;
  const ushort_t* src = &tile[dv * 72 + seg * 32];
#pragma unroll
  for (int u = 0; u < 4; u++)
    *(float4*)&dst[u * 8] = *(const float4*)&src[u * 8];
}

// ---------------------------------------------------------------------------
// Kernel 3: bf16-MFMA causal flash attention with sink; head-sum via atomics.
// ---------------------------------------------------------------------------
__global__ __launch_bounds__(256) void attn(
    const ushort_t* __restrict__ qn, const ushort_t* __restrict__ kn,
    const ushort_t* __restrict__ vt, const float* __restrict__ lobo,
    const float* __restrict__ qknf, float* __restrict__ y) {
  const int qt = blockIdx.x;
  const int h  = blockIdx.y;
  const int b  = blockIdx.z;
  const int g  = h >> 2;

  __shared__ short Qs[64 * 72];
  __shared__ short Ks[64 * 72];
  __shared__ short Vs[128 * 72];
  __shared__ short Ps[64 * 72];

  const int tid = threadIdx.x;
  const int wave = tid >> 6, lane = tid & 63;
  const int quad = lane >> 4, l16 = lane & 15;

  {
    const ushort_t* qb = qn + ((size_t)(b * H_ + h) * T_ + qt * 64) * 64;
    int r = tid >> 2, part = tid & 3;
    *(float4*)&Qs[r * 72 + part * 16] = *(const float4*)&qb[r * 64 + part * 16];
    *(float4*)&Qs[r * 72 + part * 16 + 8] =
        *(const float4*)&qb[r * 64 + part * 16 + 8];
  }

  f32x4 o[8];
#pragma unroll
  for (int nt = 0; nt < 8; nt++) o[nt] = (f32x4){0.f, 0.f, 0.f, 0.f};
  float m_i[4], l_i[4];
  const float lb = lobo[h];
  const float gsc = qknf[0];
#pragma unroll
  for (int r = 0; r < 4; r++) { m_i[r] = lb; l_i[r] = 1.0f; }

  const ushort_t* kbase = kn + ((size_t)(b * G_ + g) * T_) * 64;
  const ushort_t* vbase = vt + ((size_t)(b * G_ + g) * 128) * T_;

  for (int kt = 0; kt <= qt; kt++) {
    __syncthreads();
    {
      const ushort_t* kb = kbase + (size_t)kt * 64 * 64;
      int r = tid >> 2, part = tid & 3;
      *(float4*)&Ks[r * 72 + part * 16] = *(const float4*)&kb[r * 64 + part * 16];
      *(float4*)&Ks[r * 72 + part * 16 + 8] =
          *(const float4*)&kb[r * 64 + part * 16 + 8];
    }
    {
      int dv = tid >> 1, seg = tid & 1;
      const ushort_t* vb = vbase + (size_t)dv * T_ + kt * 64 + seg * 32;
      short* dst = &Vs[dv * 72 + seg * 32];
#pragma unroll
      for (int u = 0; u < 4; u++)
        *(float4*)&dst[u * 8] = *(const float4*)&vb[u * 8];
    }
    __syncthreads();

    f32x4 s[4];
#pragma unroll
    for (int nt = 0; nt < 4; nt++) s[nt] = (f32x4){0.f, 0.f, 0.f, 0.f};
#pragma unroll
    for (int ks = 0; ks < 2; ks++) {
      short8 aq = *(const short8*)&Qs[(wave * 16 + l16) * 72 + ks * 32 + quad * 8];
#pragma unroll
      for (int nt = 0; nt < 4; nt++) {
        short8 bk = *(const short8*)&Ks[(nt * 16 + l16) * 72 + ks * 32 + quad * 8];
        s[nt] = __builtin_amdgcn_mfma_f32_16x16x32_bf16(aq, bk, s[nt], 0, 0, 0);
      }
    }

    const bool diag = (kt == qt);
    float p[4][4], alpha[4];
#pragma unroll
    for (int r = 0; r < 4; r++) {
      int row = wave * 16 + quad * 4 + r;
      float sv[4];
#pragma unroll
      for (int nt = 0; nt < 4; nt++) {
        sv[nt] = s[nt][r] * gsc;
        if (diag && (nt * 16 + l16) > row) sv[nt] = -1e30f;
      }
      float mx = fmaxf(fmaxf(sv[0], sv[1]), fmaxf(sv[2], sv[3]));
      mx = fmaxf(mx, __shfl_xor(mx, 1, 64));
      mx = fmaxf(mx, __shfl_xor(mx, 2, 64));
      mx = fmaxf(mx, __shfl_xor(mx, 4, 64));
      mx = fmaxf(mx, __shfl_xor(mx, 8, 64));
      float mnew = fmaxf(m_i[r], mx);
      alpha[r] = __expf(m_i[r] - mnew);
      float rs = 0.f;
#pragma unroll
      for (int nt = 0; nt < 4; nt++) {
        float pv = __expf(sv[nt] - mnew);
        p[nt][r] = pv; rs += pv;
      }
      rs += __shfl_xor(rs, 1, 64);
      rs += __shfl_xor(rs, 2, 64);
      rs += __shfl_xor(rs, 4, 64);
      rs += __shfl_xor(rs, 8, 64);
      l_i[r] = l_i[r] * alpha[r] + rs;
      m_i[r] = mnew;
#pragma unroll
      for (int nv = 0; nv < 8; nv++) o[nv][r] *= alpha[r];
    }

#pragma unroll
    for (int nt = 0; nt < 4; nt++)
#pragma unroll
      for (int r = 0; r < 4; r++)
        Ps[(wave * 16 + quad * 4 + r) * 72 + nt * 16 + l16] =
            (short)f2bf(p[nt][r]);

#pragma unroll
    for (int ks = 0; ks < 2; ks++) {
      short8 ap = *(const short8*)&Ps[(wave * 16 + l16) * 72 + ks * 32 + quad * 8];
#pragma unroll
      for (int nv = 0; nv < 8; nv++) {
        short8 bv = *(const short8*)&Vs[(nv * 16 + l16) * 72 + ks * 32 + quad * 8];
        o[nv] = __builtin_amdgcn_mfma_f32_16x16x32_bf16(ap, bv, o[nv], 0, 0, 0);
      }
    }
  }

#pragma unroll
  for (int r = 0; r < 4; r++) {
    float invl = 1.0f / l_i[r];
    size_t row = (size_t)b * T_ + qt * 64 + wave * 16 + quad * 4 + r;
#pragma unroll
    for (int nv = 0; nv < 8; nv++)
      atomicAdd(&y[row * 128 + nv * 16 + l16], o[nv][r] * invl);
  }
}

// ---------------------------------------------------------------------------
// Kernel 4: out = y[B*T,128] @ Wproj[128,1024]  (fp32).
// ---------------------------------------------------------------------------
__global__ __launch_bounds__(256) void out_proj(
    const float* __restrict__ y, const float* __restrict__ Wproj,
    float* __restrict__ out) {
  __shared__ float ylds[4][128];
  const int m0 = blockIdx.x * 4;
  const int tid = threadIdx.x;
  *(float2*)&((float*)ylds)[tid * 2] = *(const float2*)&y[(size_t)m0 * 128 + tid * 2];
  __syncthreads();
  float acc[4][4];
#pragma unroll
  for (int i = 0; i < 4; i++)
#pragma unroll
    for (int j = 0; j < 4; j++) acc[i][j] = 0.0f;
  for (int k = 0; k < 128; k++) {
    float w[4];
#pragma unroll
    for (int j = 0; j < 4; j++) w[j] = Wproj[(size_t)k * 1024 + tid + 256 * j];
#pragma unroll
    for (int i = 0; i < 4; i++) {
      float yv = ylds[i][k];
#pragma unroll
      for (int j = 0; j < 4; j++) acc[i][j] += yv * w[j];
    }
  }
#pragma unroll
  for (int i = 0; i < 4; i++)
#pragma unroll
    for (int j = 0; j < 4; j++)
      out[(size_t)(m0 + i) * 1024 + tid + 256 * j] = acc[i][j];
}

// ---------------------------------------------------------------------------
extern "C" void kernel_launch(void* const* d_in, const int* in_sizes, int n_in,
                              void* d_out, int out_size, void* d_ws, size_t ws_size,
                              hipStream_t stream) {
  const float* x     = (const float*)d_in[0];
  const float* Wq    = (const float*)d_in[2];
  const float* Wk    = (const float*)d_in[3];
  const float* Wv    = (const float*)d_in[4];
  const float* Wproj = (const float*)d_in[5];
  const float* lobo  = (const float*)d_in[6];
  const float* qknf  = (const float*)d_in[7];
  float* out = (float*)d_out;

  // workspace layout (bytes): [qkv f32 | xb bf16 | wt bf16]; qn/kn/vt/y alias xb
  float* qkv = (float*)d_ws;                                    // 7,340,032 f32
  ushort_t* xb = (ushort_t*)(qkv + (size_t)B_ * T_ * NQKV);     // 12,582,912 bf16
  ushort_t* wt = xb + (size_t)B_ * T_ * KSPLIT;                 //  5,505,024 bf16
  // post-GEMM aliases (xb region is dead after gemm_qkv_mfma):
  ushort_t* qn = xb;                                            // 4,194,304 bf16
  ushort_t* kn = qn + (size_t)B_ * H_ * T_ * 64;                // 1,048,576 bf16
  ushort_t* vt = kn + (size_t)B_ * G_ * T_ * 64;                // 2,097,152 bf16
  float* y = (float*)(vt + (size_t)B_ * G_ * 128 * T_);         //   524,288 f32

  cast_x<<<(B_ * T_ * C_ / 4) / 256, 256, 0, stream>>>(x, xb);
  dim3 gw(NQKV / 64, C_ / 64);
  cast_w<<<gw, 256, 0, stream>>>(Wq, Wk, Wv, wt);

  dim3 gg(NQKV / 128, (B_ * T_) / 128);
  gemm_qkv_mfma<<<gg, 256, 0, stream>>>(xb, wt, qkv);

  int nvec = B_ * T_ * H_ + B_ * T_ * G_;   // 81920
  rope_norm<<<nvec / 4, 256, 0, stream>>>(qkv, qn, kn);

  dim3 gv(T_ / 64, B_ * G_);
  vtrans<<<gv, 256, 0, stream>>>(qkv, vt);

  hipMemsetAsync(y, 0, (size_t)B_ * T_ * 128 * sizeof(float), stream);

  dim3 ga(T_ / 64, H_, B_);
  attn<<<ga, 256, 0, stream>>>(qn, kn, vt, lobo, qknf, y);

  out_proj<<<(B_ * T_) / 4, 256, 0, stream>>>(y, Wproj, out);
}

// Round 4
// 291.359 us; speedup vs baseline: 3.9094x; 1.3945x over previous
//
#include <hip/hip_runtime.h>
#include <hip/hip_bf16.h>
#include <math.h>

#define B_ 2
#define T_ 2048
#define C_ 1024
#define H_ 16
#define G_ 4
#define DQK_ 64
#define DV_ 128
#define NQKV 1792   // H*DQK + G*DQK + G*DV
#define KSPLIT 3072 // [x_hi | x_lo | x_hi] · [w_hi ; w_hi ; w_lo]

typedef __attribute__((ext_vector_type(8))) short short8;
typedef __attribute__((ext_vector_type(4))) short short4v;
typedef __attribute__((ext_vector_type(4))) float f32x4;
typedef unsigned short ushort_t;

__device__ inline ushort_t f2bf(float f) {
  union { float f; unsigned int u; } v; v.f = f;
  unsigned int r = (v.u + 0x7FFFu + ((v.u >> 16) & 1u)) >> 16;  // RNE
  return (ushort_t)r;
}
__device__ inline float bf2f(ushort_t h) {
  union { unsigned int u; float f; } v; v.u = ((unsigned int)h) << 16;
  return v.f;
}

#define GLD_LDS16(g, l)                                              \
  __builtin_amdgcn_global_load_lds(                                  \
      (const __attribute__((address_space(1))) void*)(g),            \
      (__attribute__((address_space(3))) void*)(l), 16, 0, 0)

// ---------------------------------------------------------------------------
// Kernel 0a: split-cast x -> xb[4096][3072] bf16 = [x_hi | x_lo | x_hi]
// ---------------------------------------------------------------------------
__global__ __launch_bounds__(256) void cast_x(
    const float* __restrict__ x, ushort_t* __restrict__ xb) {
  int idx = blockIdx.x * 256 + threadIdx.x;
  int m = idx >> 8;
  int kq = (idx & 255) * 4;
  float4 v = *(const float4*)&x[(size_t)m * 1024 + kq];
  ushort_t h[4], l[4];
  float f[4] = {v.x, v.y, v.z, v.w};
#pragma unroll
  for (int c = 0; c < 4; c++) {
    h[c] = f2bf(f[c]);
    l[c] = f2bf(f[c] - bf2f(h[c]));
  }
  short4v hv = {(short)h[0], (short)h[1], (short)h[2], (short)h[3]};
  short4v lv = {(short)l[0], (short)l[1], (short)l[2], (short)l[3]};
  ushort_t* row = xb + (size_t)m * KSPLIT;
  *(short4v*)&row[kq] = hv;
  *(short4v*)&row[1024 + kq] = lv;
  *(short4v*)&row[2048 + kq] = hv;
}

// ---------------------------------------------------------------------------
// Kernel 0b: transpose+split-cast W -> wt[1792][3072] bf16.
// ---------------------------------------------------------------------------
__global__ __launch_bounds__(256) void cast_w(
    const float* __restrict__ Wq, const float* __restrict__ Wk,
    const float* __restrict__ Wv, ushort_t* __restrict__ wt) {
  __shared__ float tile[64][65];
  const int n0 = blockIdx.x * 64;
  const int k0 = blockIdx.y * 64;
  const int tid = threadIdx.x;

  const float* Wp; int ldw, noff;
  if (n0 < 1024)      { Wp = Wq; ldw = 1024; noff = n0; }
  else if (n0 < 1280) { Wp = Wk; ldw = 256;  noff = n0 - 1024; }
  else                { Wp = Wv; ldw = 512;  noff = n0 - 1280; }

#pragma unroll
  for (int it = 0; it < 4; it++) {
    int fi = it * 256 + tid;
    int kk = fi >> 4;
    int nc = (fi & 15) * 4;
    float4 v = *(const float4*)&Wp[(size_t)(k0 + kk) * ldw + noff + nc];
    tile[nc + 0][kk] = v.x; tile[nc + 1][kk] = v.y;
    tile[nc + 2][kk] = v.z; tile[nc + 3][kk] = v.w;
  }
  __syncthreads();
  int nn = tid >> 2, seg = tid & 3;
  ushort_t hb[16], lb[16];
#pragma unroll
  for (int u = 0; u < 16; u++) {
    float f = tile[nn][seg * 16 + u];
    hb[u] = f2bf(f);
    lb[u] = f2bf(f - bf2f(hb[u]));
  }
  ushort_t* row = wt + (size_t)(n0 + nn) * KSPLIT + k0 + seg * 16;
  *(float4*)&row[0] = *(float4*)&hb[0];
  *(float4*)&row[8] = *(float4*)&hb[8];
  *(float4*)&row[1024] = *(float4*)&hb[0];
  *(float4*)&row[1024 + 8] = *(float4*)&hb[8];
  *(float4*)&row[2048] = *(float4*)&lb[0];
  *(float4*)&row[2048 + 8] = *(float4*)&lb[8];
}

// ---------------------------------------------------------------------------
// Kernel 1: bf16-MFMA QKV GEMM.  qkv[4096][1792] = xb @ wt^T  (unchanged)
// ---------------------------------------------------------------------------
__global__ __launch_bounds__(256) void gemm_qkv_mfma(
    const ushort_t* __restrict__ xb, const ushort_t* __restrict__ wt,
    float* __restrict__ qkv) {
  __shared__ ushort_t At[128 * 32];
  __shared__ ushort_t Bt[128 * 32];
  const int tid = threadIdx.x;
  const int wave = tid >> 6, lane = tid & 63;
  const int quad = lane >> 4, l16 = lane & 15;
  const int m0 = blockIdx.y * 128, n0 = blockIdx.x * 128;
  const int wm = (wave & 1) * 64, wn = (wave >> 1) * 64;

  f32x4 acc[4][4];
#pragma unroll
  for (int i = 0; i < 4; i++)
#pragma unroll
    for (int j = 0; j < 4; j++) acc[i][j] = (f32x4){0.f, 0.f, 0.f, 0.f};

  const int rA = wave * 32 + (lane >> 2);
  const int cA = (lane & 3) * 8;
  const ushort_t* gA = xb + (size_t)(m0 + rA) * KSPLIT + cA;
  const ushort_t* gB = wt + (size_t)(n0 + rA) * KSPLIT + cA;
  ushort_t* lA0 = At + (size_t)(wave * 32) * 32;
  ushort_t* lA1 = At + (size_t)(wave * 32 + 16) * 32;
  ushort_t* lB0 = Bt + (size_t)(wave * 32) * 32;
  ushort_t* lB1 = Bt + (size_t)(wave * 32 + 16) * 32;

  for (int kt = 0; kt < KSPLIT / 32; kt++) {
    __syncthreads();
    const ushort_t* a = gA + kt * 32;
    const ushort_t* b = gB + kt * 32;
    GLD_LDS16(a, lA0);
    GLD_LDS16(a + 16 * KSPLIT, lA1);
    GLD_LDS16(b, lB0);
    GLD_LDS16(b + 16 * KSPLIT, lB1);
    __syncthreads();

    short8 af[4], bf[4];
#pragma unroll
    for (int i = 0; i < 4; i++)
      af[i] = *(const short8*)&At[(wm + 16 * i + l16) * 32 + quad * 8];
#pragma unroll
    for (int j = 0; j < 4; j++)
      bf[j] = *(const short8*)&Bt[(wn + 16 * j + l16) * 32 + quad * 8];
#pragma unroll
    for (int i = 0; i < 4; i++)
#pragma unroll
      for (int j = 0; j < 4; j++)
        acc[i][j] = __builtin_amdgcn_mfma_f32_16x16x32_bf16(
            af[i], bf[j], acc[i][j], 0, 0, 0);
  }

#pragma unroll
  for (int i = 0; i < 4; i++) {
    int m = m0 + wm + 16 * i + quad * 4;
#pragma unroll
    for (int j = 0; j < 4; j++) {
      int n = n0 + wn + 16 * j + l16;
#pragma unroll
      for (int r = 0; r < 4; r++)
        qkv[(size_t)(m + r) * NQKV + n] = acc[i][j][r];
    }
  }
}

// ---------------------------------------------------------------------------
// Kernel 2: RoPE + qk-norm -> unit-norm bf16 q,k in MFMA-fragment layouts.
// qf per (b,h): [qt(32)][wave(4)][ks(2)][quad(4)][l16(16)][j(8)]
// kf per (b,g): [kt(32)][ks(2)][nt(4)][quad(4)][l16(16)][j(8)]
// ---------------------------------------------------------------------------
__global__ __launch_bounds__(256) void rope_norm(
    const float* __restrict__ qkv,
    ushort_t* __restrict__ qf, ushort_t* __restrict__ kf) {
  const int NQ = B_ * T_ * H_;
  int vec = blockIdx.x * 4 + (threadIdx.x >> 6);
  int d = threadIdx.x & 63;

  float val; int t, b, isq; ushort_t* dstbase;
  if (vec < NQ) {
    int h = vec % H_; int bt = vec / H_;
    t = bt % T_; b = bt / T_;
    val = qkv[(size_t)bt * NQKV + h * 64 + d];
    dstbase = qf + (size_t)(b * 16 + h) * 131072;
    isq = 1;
  } else {
    int vk = vec - NQ;
    int g = vk % G_; int bt = vk / G_;
    t = bt % T_; b = bt / T_;
    val = qkv[(size_t)bt * NQKV + 1024 + g * 64 + d];
    dstbase = kf + (size_t)(b * 4 + g) * 131072;
    isq = 0;
  }
  int i = d & 31;
  float inv = powf(10000.0f, -(float)(2 * i) * (1.0f / 64.0f));
  float ang = (float)t * inv;
  float cs = cosf(ang), sn = sinf(ang);
  float partner = __shfl(val, d ^ 32, 64);
  float r = (d < 32) ? (val * cs - partner * sn) : (val * cs + partner * sn);
  float ss = r * r;
#pragma unroll
  for (int off = 32; off; off >>= 1) ss += __shfl_xor(ss, off, 64);
  r *= 1.0f / (sqrtf(ss) + 1e-6f);

  int kt = t >> 6, tt = t & 63;
  int l16v = tt & 15;
  int ks = d >> 5, quad = (d >> 3) & 3, j = d & 7;
  size_t off2;
  if (isq) {
    int wavei = tt >> 4;
    off2 = ((size_t)(kt * 8 + wavei * 2 + ks) * 4 + quad) * 128 + l16v * 8 + j;
  } else {
    int nt = tt >> 4;
    off2 = ((size_t)(kt * 8 + ks * 4 + nt) * 4 + quad) * 128 + l16v * 8 + j;
  }
  dstbase[off2] = f2bf(r);
}

// ---------------------------------------------------------------------------
// Kernel 2b: V scatter + bf16 cast into PV B-fragment layout.
// vf per (b,g): [kt(32)][ks(2)][nv(8)][quad(4)][l16(16)][j(8)]
//   element (t, dv): ks=(t>>5)&1, quad=(t>>3)&3, j=t&7, nv=dv>>4, l16=dv&15
// ---------------------------------------------------------------------------
__global__ __launch_bounds__(256) void vscatter(
    const float* __restrict__ qkv, ushort_t* __restrict__ vf) {
  int idx = blockIdx.x * 256 + threadIdx.x;   // 2,097,152
  int dv = idx & 127;
  int t = (idx >> 7) & 2047;
  int g = (idx >> 18) & 3;
  int b = idx >> 20;
  float v = qkv[(size_t)(b * T_ + t) * NQKV + 1280 + g * 128 + dv];
  int kt = t >> 6, ks = (t >> 5) & 1, quad = (t >> 3) & 3, j = t & 7;
  int nv = dv >> 4, l16v = dv & 15;
  size_t off = ((size_t)(kt * 16 + ks * 8 + nv) * 4 + quad) * 128 + l16v * 8 + j;
  vf[(size_t)(b * 4 + g) * 262144 + off] = f2bf(v);
}

// ---------------------------------------------------------------------------
// Kernel 3: bf16-MFMA causal flash attention, FIXED-MAX softmax (m = gsc,
// valid since |q̂·k̂| <= 1 and sink logit lobo < gsc), l via ones-column MFMA.
// Block = 4 waves, 64 Q rows of one (b,h); Q in registers; K/V staged with
// global_load_lds into fragment-order LDS (conflict-free, unpadded).
// ---------------------------------------------------------------------------
__global__ __launch_bounds__(256) void attn(
    const ushort_t* __restrict__ qf, const ushort_t* __restrict__ kf,
    const ushort_t* __restrict__ vf, const float* __restrict__ lobo,
    const float* __restrict__ qknf, float* __restrict__ y) {
  const int f = blockIdx.x;
  const int b = f >> 9;
  const int h = (f >> 5) & 15;
  const int qt = ((f & 31) + 8 * (f >> 8)) & 31;   // spread qt across CUs
  const int g = h >> 2;

  __shared__ ushort_t Ks[8 * 512];     // 8 KB  (fragment blocks ks*4+nt)
  __shared__ ushort_t Vs[16 * 512];    // 16 KB (fragment blocks ks*8+nv)
  __shared__ ushort_t Vones[512];      // ones-column tile (l via MFMA)
  __shared__ ushort_t Ps[64 * 68];     // 8.5 KB, stride 68 kills conflicts

  const int tid = threadIdx.x;
  const int wave = tid >> 6, lane = tid & 63;
  const int quad = lane >> 4, l16 = lane & 15;

  if (tid < 64) {
    ushort_t vv = ((tid & 15) == 0) ? (ushort_t)0x3F80 : (ushort_t)0;
#pragma unroll
    for (int u = 0; u < 8; u++) Vones[tid * 8 + u] = vv;
  }

  // Q A-fragments -> registers (held across whole K loop)
  const ushort_t* qb =
      qf + ((size_t)((b * 16 + h) * 32 + qt) * 8 + wave * 2) * 512;
  short8 aq0 = *(const short8*)&qb[lane * 8];
  short8 aq1 = *(const short8*)&qb[512 + lane * 8];

  f32x4 o[9];
#pragma unroll
  for (int nv = 0; nv < 9; nv++) o[nv] = (f32x4){0.f, 0.f, 0.f, 0.f};

  const float gsc = qknf[0];
  const float sinkp = __expf(lobo[h] - gsc);

  const ushort_t* kt0 = kf + (size_t)(b * 4 + g) * 131072;
  const ushort_t* vt0 = vf + (size_t)(b * 4 + g) * 262144;

  for (int kt = 0; kt <= qt; kt++) {
    __syncthreads();   // all waves done reading previous Ks/Vs
    const ushort_t* kg = kt0 + (size_t)kt * 4096;
    const ushort_t* vg = vt0 + (size_t)kt * 8192;
    GLD_LDS16(kg + (wave * 2 + 0) * 512 + lane * 8, &Ks[(wave * 2 + 0) * 512]);
    GLD_LDS16(kg + (wave * 2 + 1) * 512 + lane * 8, &Ks[(wave * 2 + 1) * 512]);
#pragma unroll
    for (int u = 0; u < 4; u++)
      GLD_LDS16(vg + (wave * 4 + u) * 512 + lane * 8,
                &Vs[(wave * 4 + u) * 512]);
    __syncthreads();   // vmcnt(0) drain -> staged data visible

    // S = Q K^T (16 rows x 64 keys per wave)
    f32x4 s[4];
#pragma unroll
    for (int nt = 0; nt < 4; nt++) s[nt] = (f32x4){0.f, 0.f, 0.f, 0.f};
#pragma unroll
    for (int nt = 0; nt < 4; nt++) {
      short8 bk = *(const short8*)&Ks[nt * 512 + lane * 8];
      s[nt] = __builtin_amdgcn_mfma_f32_16x16x32_bf16(aq0, bk, s[nt], 0, 0, 0);
    }
#pragma unroll
    for (int nt = 0; nt < 4; nt++) {
      short8 bk = *(const short8*)&Ks[(4 + nt) * 512 + lane * 8];
      s[nt] = __builtin_amdgcn_mfma_f32_16x16x32_bf16(aq1, bk, s[nt], 0, 0, 0);
    }

    // fixed-max softmax: p = exp(gsc*(s-1)); masked -> 0
    const bool diag = (kt == qt);
#pragma unroll
    for (int nt = 0; nt < 4; nt++)
#pragma unroll
      for (int r = 0; r < 4; r++) {
        float p = __expf((s[nt][r] - 1.0f) * gsc);
        if (diag && (nt * 16 + l16) > (wave * 16 + quad * 4 + r)) p = 0.f;
        Ps[(wave * 16 + quad * 4 + r) * 68 + nt * 16 + l16] = f2bf(p);
      }

    // O += P V   (per-wave P region; no inter-wave barrier needed)
    short8 ap0 = *(const short8*)&Ps[(wave * 16 + l16) * 68 + quad * 8];
    short8 ap1 = *(const short8*)&Ps[(wave * 16 + l16) * 68 + 32 + quad * 8];
#pragma unroll
    for (int nv = 0; nv < 8; nv++) {
      short8 bv = *(const short8*)&Vs[nv * 512 + lane * 8];
      o[nv] = __builtin_amdgcn_mfma_f32_16x16x32_bf16(ap0, bv, o[nv], 0, 0, 0);
    }
    {
      short8 bo = *(const short8*)&Vones[lane * 8];
      o[8] = __builtin_amdgcn_mfma_f32_16x16x32_bf16(ap0, bo, o[8], 0, 0, 0);
      o[8] = __builtin_amdgcn_mfma_f32_16x16x32_bf16(ap1, bo, o[8], 0, 0, 0);
    }
#pragma unroll
    for (int nv = 0; nv < 8; nv++) {
      short8 bv = *(const short8*)&Vs[(8 + nv) * 512 + lane * 8];
      o[nv] = __builtin_amdgcn_mfma_f32_16x16x32_bf16(ap1, bv, o[nv], 0, 0, 0);
    }
  }

  // epilogue: l = sink + mfma row-sum (col 0 of o[8]); normalize; head-sum
#pragma unroll
  for (int r = 0; r < 4; r++) {
    float lm = __shfl(o[8][r], lane & 48, 64);   // from l16==0 lane of my quad
    float invl = 1.0f / (lm + sinkp);
    size_t row = (size_t)b * T_ + qt * 64 + wave * 16 + quad * 4 + r;
#pragma unroll
    for (int nv = 0; nv < 8; nv++)
      atomicAdd(&y[row * 128 + nv * 16 + l16], o[nv][r] * invl);
  }
}

// ---------------------------------------------------------------------------
// Kernel 4: out = y[B*T,128] @ Wproj[128,1024]  (fp32).
// ---------------------------------------------------------------------------
__global__ __launch_bounds__(256) void out_proj(
    const float* __restrict__ y, const float* __restrict__ Wproj,
    float* __restrict__ out) {
  __shared__ float ylds[4][128];
  const int m0 = blockIdx.x * 4;
  const int tid = threadIdx.x;
  *(float2*)&((float*)ylds)[tid * 2] = *(const float2*)&y[(size_t)m0 * 128 + tid * 2];
  __syncthreads();
  float acc[4][4];
#pragma unroll
  for (int i = 0; i < 4; i++)
#pragma unroll
    for (int j = 0; j < 4; j++) acc[i][j] = 0.0f;
  for (int k = 0; k < 128; k++) {
    float w[4];
#pragma unroll
    for (int j = 0; j < 4; j++) w[j] = Wproj[(size_t)k * 1024 + tid + 256 * j];
#pragma unroll
    for (int i = 0; i < 4; i++) {
      float yv = ylds[i][k];
#pragma unroll
      for (int j = 0; j < 4; j++) acc[i][j] += yv * w[j];
    }
  }
#pragma unroll
  for (int i = 0; i < 4; i++)
#pragma unroll
    for (int j = 0; j < 4; j++)
      out[(size_t)(m0 + i) * 1024 + tid + 256 * j] = acc[i][j];
}

// ---------------------------------------------------------------------------
extern "C" void kernel_launch(void* const* d_in, const int* in_sizes, int n_in,
                              void* d_out, int out_size, void* d_ws, size_t ws_size,
                              hipStream_t stream) {
  const float* x     = (const float*)d_in[0];
  const float* Wq    = (const float*)d_in[2];
  const float* Wk    = (const float*)d_in[3];
  const float* Wv    = (const float*)d_in[4];
  const float* Wproj = (const float*)d_in[5];
  const float* lobo  = (const float*)d_in[6];
  const float* qknf  = (const float*)d_in[7];
  float* out = (float*)d_out;

  // workspace: [qkv f32 | xb bf16 | wt bf16]; qf/kf/vf/y alias xb after GEMM
  float* qkv = (float*)d_ws;                                    // 7,340,032 f32
  ushort_t* xb = (ushort_t*)(qkv + (size_t)B_ * T_ * NQKV);     // 12,582,912 bf16
  ushort_t* wt = xb + (size_t)B_ * T_ * KSPLIT;                 //  5,505,024 bf16
  ushort_t* qf = xb;                                            // 4,194,304 bf16
  ushort_t* kf = qf + (size_t)B_ * H_ * T_ * 64;                // 1,048,576 bf16
  ushort_t* vf = kf + (size_t)B_ * G_ * T_ * 64;                // 2,097,152 bf16
  float* y = (float*)(vf + (size_t)B_ * G_ * T_ * 128);         //   524,288 f32

  cast_x<<<(B_ * T_ * C_ / 4) / 256, 256, 0, stream>>>(x, xb);
  dim3 gw(NQKV / 64, C_ / 64);
  cast_w<<<gw, 256, 0, stream>>>(Wq, Wk, Wv, wt);

  dim3 gg(NQKV / 128, (B_ * T_) / 128);
  gemm_qkv_mfma<<<gg, 256, 0, stream>>>(xb, wt, qkv);

  int nvec = B_ * T_ * H_ + B_ * T_ * G_;   // 81920
  rope_norm<<<nvec / 4, 256, 0, stream>>>(qkv, qf, kf);

  vscatter<<<(B_ * G_ * T_ * DV_) / 256, 256, 0, stream>>>(qkv, vf);

  hipMemsetAsync(y, 0, (size_t)B_ * T_ * 128 * sizeof(float), stream);

  attn<<<B_ * H_ * (T_ / 64), 256, 0, stream>>>(qf, kf, vf, lobo, qknf, y);

  out_proj<<<(B_ * T_) / 4, 256, 0, stream>>>(y, Wproj, out);
}

// Round 6
// 284.015 us; speedup vs baseline: 4.0105x; 1.0259x over previous
//
#include <hip/hip_runtime.h>
#include <hip/hip_bf16.h>
#include <math.h>

#define B_ 2
#define T_ 2048
#define C_ 1024
#define H_ 16
#define G_ 4
#define DQK_ 64
#define DV_ 128
#define NQKV 1792   // H*DQK + G*DQK + G*DV
#define KS2 2048    // compact split storage: [hi | lo]
// Logical GEMM K = 3072 tiles 0..95: s0=hi·hi (0..31), s1=lo·hi (32..63),
// s2=hi·lo (64..95). Column remap: ktA = kt<64?kt:kt-64; ktB = kt<32?kt:kt-32.

typedef __attribute__((ext_vector_type(8))) short short8;
typedef __attribute__((ext_vector_type(4))) short short4v;
typedef __attribute__((ext_vector_type(4))) float f32x4;
typedef unsigned short ushort_t;

__device__ inline ushort_t f2bf(float f) {
  union { float f; unsigned int u; } v; v.f = f;
  unsigned int r = (v.u + 0x7FFFu + ((v.u >> 16) & 1u)) >> 16;  // RNE
  return (ushort_t)r;
}
__device__ inline float bf2f(ushort_t h) {
  union { unsigned int u; float f; } v; v.u = ((unsigned int)h) << 16;
  return v.f;
}

#define GLD_LDS16(g, l)                                              \
  __builtin_amdgcn_global_load_lds(                                  \
      (const __attribute__((address_space(1))) void*)(g),            \
      (__attribute__((address_space(3))) void*)(l), 16, 0, 0)

// ---------------------------------------------------------------------------
// Kernel 0a: split-cast x -> xb[4096][2048] bf16 = [x_hi | x_lo]
// ---------------------------------------------------------------------------
__global__ __launch_bounds__(256) void cast_x(
    const float* __restrict__ x, ushort_t* __restrict__ xb) {
  int idx = blockIdx.x * 256 + threadIdx.x;
  int m = idx >> 8;
  int kq = (idx & 255) * 4;
  float4 v = *(const float4*)&x[(size_t)m * 1024 + kq];
  ushort_t h[4], l[4];
  float f[4] = {v.x, v.y, v.z, v.w};
#pragma unroll
  for (int c = 0; c < 4; c++) {
    h[c] = f2bf(f[c]);
    l[c] = f2bf(f[c] - bf2f(h[c]));
  }
  short4v hv = {(short)h[0], (short)h[1], (short)h[2], (short)h[3]};
  short4v lv = {(short)l[0], (short)l[1], (short)l[2], (short)l[3]};
  ushort_t* row = xb + (size_t)m * KS2;
  *(short4v*)&row[kq] = hv;
  *(short4v*)&row[1024 + kq] = lv;
}

// ---------------------------------------------------------------------------
// Kernel 0b: transpose+split-cast W -> wt[1792][2048] bf16 = [w_hi | w_lo]
// ---------------------------------------------------------------------------
__global__ __launch_bounds__(256) void cast_w(
    const float* __restrict__ Wq, const float* __restrict__ Wk,
    const float* __restrict__ Wv, ushort_t* __restrict__ wt) {
  __shared__ float tile[64][65];
  const int n0 = blockIdx.x * 64;
  const int k0 = blockIdx.y * 64;
  const int tid = threadIdx.x;

  const float* Wp; int ldw, noff;
  if (n0 < 1024)      { Wp = Wq; ldw = 1024; noff = n0; }
  else if (n0 < 1280) { Wp = Wk; ldw = 256;  noff = n0 - 1024; }
  else                { Wp = Wv; ldw = 512;  noff = n0 - 1280; }

#pragma unroll
  for (int it = 0; it < 4; it++) {
    int fi = it * 256 + tid;
    int kk = fi >> 4;
    int nc = (fi & 15) * 4;
    float4 v = *(const float4*)&Wp[(size_t)(k0 + kk) * ldw + noff + nc];
    tile[nc + 0][kk] = v.x; tile[nc + 1][kk] = v.y;
    tile[nc + 2][kk] = v.z; tile[nc + 3][kk] = v.w;
  }
  __syncthreads();
  int nn = tid >> 2, seg = tid & 3;
  ushort_t hb[16], lb[16];
#pragma unroll
  for (int u = 0; u < 16; u++) {
    float f = tile[nn][seg * 16 + u];
    hb[u] = f2bf(f);
    lb[u] = f2bf(f - bf2f(hb[u]));
  }
  ushort_t* row = wt + (size_t)(n0 + nn) * KS2 + k0 + seg * 16;
  *(float4*)&row[0] = *(float4*)&hb[0];
  *(float4*)&row[8] = *(float4*)&hb[8];
  *(float4*)&row[1024] = *(float4*)&lb[0];
  *(float4*)&row[1024 + 8] = *(float4*)&lb[8];
}

// ---------------------------------------------------------------------------
// Kernel 1: bf16-MFMA QKV GEMM, split-K=2 (blockIdx.z = kh).
// kh=0: K-tiles 0..47  -> qkv0 (f32 plain store)
// kh=1: K-tiles 48..95 -> qkv1c (bf16 store; correction terms are ~1e-3 of
//       main so bf16 rounding is negligible). Consumers sum both.
// ---------------------------------------------------------------------------
__global__ __launch_bounds__(256) void gemm_qkv_mfma(
    const ushort_t* __restrict__ xb, const ushort_t* __restrict__ wt,
    float* __restrict__ qkv0, ushort_t* __restrict__ qkv1c) {
  __shared__ ushort_t At[128 * 32];
  __shared__ ushort_t Bt[128 * 32];
  const int tid = threadIdx.x;
  const int wave = tid >> 6, lane = tid & 63;
  const int quad = lane >> 4, l16 = lane & 15;
  const int m0 = blockIdx.y * 128, n0 = blockIdx.x * 128;
  const int kh = blockIdx.z;
  const int wm = (wave & 1) * 64, wn = (wave >> 1) * 64;

  f32x4 acc[4][4];
#pragma unroll
  for (int i = 0; i < 4; i++)
#pragma unroll
    for (int j = 0; j < 4; j++) acc[i][j] = (f32x4){0.f, 0.f, 0.f, 0.f};

  const int rA = wave * 32 + (lane >> 2);
  const int cA = (lane & 3) * 8;
  const ushort_t* gA = xb + (size_t)(m0 + rA) * KS2 + cA;
  const ushort_t* gB = wt + (size_t)(n0 + rA) * KS2 + cA;
  ushort_t* lA0 = At + (size_t)(wave * 32) * 32;
  ushort_t* lA1 = At + (size_t)(wave * 32 + 16) * 32;
  ushort_t* lB0 = Bt + (size_t)(wave * 32) * 32;
  ushort_t* lB1 = Bt + (size_t)(wave * 32 + 16) * 32;

  for (int kt0 = 0; kt0 < 48; kt0++) {
    const int kt = kh * 48 + kt0;
    const int ca = (kt < 64 ? kt : kt - 64) * 32;
    const int cb = (kt < 32 ? kt : kt - 32) * 32;
    __syncthreads();
    GLD_LDS16(gA + ca, lA0);
    GLD_LDS16(gA + ca + 16 * KS2, lA1);
    GLD_LDS16(gB + cb, lB0);
    GLD_LDS16(gB + cb + 16 * KS2, lB1);
    __syncthreads();

    short8 af[4], bf[4];
#pragma unroll
    for (int i = 0; i < 4; i++)
      af[i] = *(const short8*)&At[(wm + 16 * i + l16) * 32 + quad * 8];
#pragma unroll
    for (int j = 0; j < 4; j++)
      bf[j] = *(const short8*)&Bt[(wn + 16 * j + l16) * 32 + quad * 8];
#pragma unroll
    for (int i = 0; i < 4; i++)
#pragma unroll
      for (int j = 0; j < 4; j++)
        acc[i][j] = __builtin_amdgcn_mfma_f32_16x16x32_bf16(
            af[i], bf[j], acc[i][j], 0, 0, 0);
  }

  if (kh == 0) {
#pragma unroll
    for (int i = 0; i < 4; i++) {
      int m = m0 + wm + 16 * i + quad * 4;
#pragma unroll
      for (int j = 0; j < 4; j++) {
        int n = n0 + wn + 16 * j + l16;
#pragma unroll
        for (int r = 0; r < 4; r++)
          qkv0[(size_t)(m + r) * NQKV + n] = acc[i][j][r];
      }
    }
  } else {
#pragma unroll
    for (int i = 0; i < 4; i++) {
      int m = m0 + wm + 16 * i + quad * 4;
#pragma unroll
      for (int j = 0; j < 4; j++) {
        int n = n0 + wn + 16 * j + l16;
#pragma unroll
        for (int r = 0; r < 4; r++)
          qkv1c[(size_t)(m + r) * NQKV + n] = f2bf(acc[i][j][r]);
      }
    }
  }
}

// ---------------------------------------------------------------------------
// Kernel 2: RoPE + qk-norm -> unit-norm bf16 q,k in MFMA-fragment layouts.
// Reads qkv = qkv0 + qkv1c (split-K halves).
// ---------------------------------------------------------------------------
__global__ __launch_bounds__(256) void rope_norm(
    const float* __restrict__ qkv0, const ushort_t* __restrict__ qkv1c,
    ushort_t* __restrict__ qf, ushort_t* __restrict__ kf) {
  const int NQ = B_ * T_ * H_;
  int vec = blockIdx.x * 4 + (threadIdx.x >> 6);
  int d = threadIdx.x & 63;

  size_t src; int t, b, isq; ushort_t* dstbase;
  if (vec < NQ) {
    int h = vec % H_; int bt = vec / H_;
    t = bt % T_; b = bt / T_;
    src = (size_t)bt * NQKV + h * 64 + d;
    dstbase = qf + (size_t)(b * 16 + h) * 131072;
    isq = 1;
  } else {
    int vk = vec - NQ;
    int g = vk % G_; int bt = vk / G_;
    t = bt % T_; b = bt / T_;
    src = (size_t)bt * NQKV + 1024 + g * 64 + d;
    dstbase = kf + (size_t)(b * 4 + g) * 131072;
    isq = 0;
  }
  float val = qkv0[src] + bf2f(qkv1c[src]);
  int i = d & 31;
  float inv = exp2f(-(float)i * 0.4152410118074239f);  // log2(10000)/32
  float ang = (float)t * inv;
  float sn, cs;
  __sincosf(ang, &sn, &cs);
  float partner = __shfl(val, d ^ 32, 64);
  float r = (d < 32) ? (val * cs - partner * sn) : (val * cs + partner * sn);
  float ss = r * r;
#pragma unroll
  for (int off = 32; off; off >>= 1) ss += __shfl_xor(ss, off, 64);
  r *= 1.0f / (sqrtf(ss) + 1e-6f);

  int kt = t >> 6, tt = t & 63;
  int l16v = tt & 15;
  int ks = d >> 5, quad = (d >> 3) & 3, j = d & 7;
  size_t off2;
  if (isq) {
    int wavei = tt >> 4;
    off2 = ((size_t)(kt * 8 + wavei * 2 + ks) * 4 + quad) * 128 + l16v * 8 + j;
  } else {
    int nt = tt >> 4;
    off2 = ((size_t)(kt * 8 + ks * 4 + nt) * 4 + quad) * 128 + l16v * 8 + j;
  }
  dstbase[off2] = f2bf(r);
}

// ---------------------------------------------------------------------------
// Kernel 2b: V scatter + bf16 cast into PV B-fragment layout.
// ---------------------------------------------------------------------------
__global__ __launch_bounds__(256) void vscatter(
    const float* __restrict__ qkv0, const ushort_t* __restrict__ qkv1c,
    ushort_t* __restrict__ vf) {
  int idx = blockIdx.x * 256 + threadIdx.x;   // 2,097,152
  int dv = idx & 127;
  int t = (idx >> 7) & 2047;
  int g = (idx >> 18) & 3;
  int b = idx >> 20;
  size_t src = (size_t)(b * T_ + t) * NQKV + 1280 + g * 128 + dv;
  float v = qkv0[src] + bf2f(qkv1c[src]);
  int kt = t >> 6, ks = (t >> 5) & 1, quad = (t >> 3) & 3, j = t & 7;
  int nv = dv >> 4, l16v = dv & 15;
  size_t off = ((size_t)(kt * 16 + ks * 8 + nv) * 4 + quad) * 128 + l16v * 8 + j;
  vf[(size_t)(b * 4 + g) * 262144 + off] = f2bf(v);
}

// ---------------------------------------------------------------------------
// Kernel 3: bf16-MFMA causal flash attention, fixed-max softmax (m = gsc),
// l via ones-column MFMA.
// ---------------------------------------------------------------------------
__global__ __launch_bounds__(256) void attn(
    const ushort_t* __restrict__ qf, const ushort_t* __restrict__ kf,
    const ushort_t* __restrict__ vf, const float* __restrict__ lobo,
    const float* __restrict__ qknf, float* __restrict__ y) {
  const int f = blockIdx.x;
  const int b = f >> 9;
  const int h = (f >> 5) & 15;
  const int qt = ((f & 31) + 8 * (f >> 8)) & 31;
  const int g = h >> 2;

  __shared__ ushort_t Ks[8 * 512];
  __shared__ ushort_t Vs[16 * 512];
  __shared__ ushort_t Vones[512];
  __shared__ ushort_t Ps[64 * 68];

  const int tid = threadIdx.x;
  const int wave = tid >> 6, lane = tid & 63;
  const int quad = lane >> 4, l16 = lane & 15;

  if (tid < 64) {
    ushort_t vv = ((tid & 15) == 0) ? (ushort_t)0x3F80 : (ushort_t)0;
#pragma unroll
    for (int u = 0; u < 8; u++) Vones[tid * 8 + u] = vv;
  }

  const ushort_t* qb =
      qf + ((size_t)((b * 16 + h) * 32 + qt) * 8 + wave * 2) * 512;
  short8 aq0 = *(const short8*)&qb[lane * 8];
  short8 aq1 = *(const short8*)&qb[512 + lane * 8];

  f32x4 o[9];
#pragma unroll
  for (int nv = 0; nv < 9; nv++) o[nv] = (f32x4){0.f, 0.f, 0.f, 0.f};

  const float gsc = qknf[0];
  const float sinkp = __expf(lobo[h] - gsc);

  const ushort_t* kt0 = kf + (size_t)(b * 4 + g) * 131072;
  const ushort_t* vt0 = vf + (size_t)(b * 4 + g) * 262144;

  for (int kt = 0; kt <= qt; kt++) {
    __syncthreads();
    const ushort_t* kg = kt0 + (size_t)kt * 4096;
    const ushort_t* vg = vt0 + (size_t)kt * 8192;
    GLD_LDS16(kg + (wave * 2 + 0) * 512 + lane * 8, &Ks[(wave * 2 + 0) * 512]);
    GLD_LDS16(kg + (wave * 2 + 1) * 512 + lane * 8, &Ks[(wave * 2 + 1) * 512]);
#pragma unroll
    for (int u = 0; u < 4; u++)
      GLD_LDS16(vg + (wave * 4 + u) * 512 + lane * 8,
                &Vs[(wave * 4 + u) * 512]);
    __syncthreads();

    f32x4 s[4];
#pragma unroll
    for (int nt = 0; nt < 4; nt++) s[nt] = (f32x4){0.f, 0.f, 0.f, 0.f};
#pragma unroll
    for (int nt = 0; nt < 4; nt++) {
      short8 bk = *(const short8*)&Ks[nt * 512 + lane * 8];
      s[nt] = __builtin_amdgcn_mfma_f32_16x16x32_bf16(aq0, bk, s[nt], 0, 0, 0);
    }
#pragma unroll
    for (int nt = 0; nt < 4; nt++) {
      short8 bk = *(const short8*)&Ks[(4 + nt) * 512 + lane * 8];
      s[nt] = __builtin_amdgcn_mfma_f32_16x16x32_bf16(aq1, bk, s[nt], 0, 0, 0);
    }

    const bool diag = (kt == qt);
#pragma unroll
    for (int nt = 0; nt < 4; nt++)
#pragma unroll
      for (int r = 0; r < 4; r++) {
        float p = __expf((s[nt][r] - 1.0f) * gsc);
        if (diag && (nt * 16 + l16) > (wave * 16 + quad * 4 + r)) p = 0.f;
        Ps[(wave * 16 + quad * 4 + r) * 68 + nt * 16 + l16] = f2bf(p);
      }

    short8 ap0 = *(const short8*)&Ps[(wave * 16 + l16) * 68 + quad * 8];
    short8 ap1 = *(const short8*)&Ps[(wave * 16 + l16) * 68 + 32 + quad * 8];
#pragma unroll
    for (int nv = 0; nv < 8; nv++) {
      short8 bv = *(const short8*)&Vs[nv * 512 + lane * 8];
      o[nv] = __builtin_amdgcn_mfma_f32_16x16x32_bf16(ap0, bv, o[nv], 0, 0, 0);
    }
    {
      short8 bo = *(const short8*)&Vones[lane * 8];
      o[8] = __builtin_amdgcn_mfma_f32_16x16x32_bf16(ap0, bo, o[8], 0, 0, 0);
      o[8] = __builtin_amdgcn_mfma_f32_16x16x32_bf16(ap1, bo, o[8], 0, 0, 0);
    }
#pragma unroll
    for (int nv = 0; nv < 8; nv++) {
      short8 bv = *(const short8*)&Vs[(8 + nv) * 512 + lane * 8];
      o[nv] = __builtin_amdgcn_mfma_f32_16x16x32_bf16(ap1, bv, o[nv], 0, 0, 0);
    }
  }

#pragma unroll
  for (int r = 0; r < 4; r++) {
    float lm = __shfl(o[8][r], lane & 48, 64);
    float invl = 1.0f / (lm + sinkp);
    size_t row = (size_t)b * T_ + qt * 64 + wave * 16 + quad * 4 + r;
#pragma unroll
    for (int nv = 0; nv < 8; nv++)
      atomicAdd(&y[row * 128 + nv * 16 + l16], o[nv][r] * invl);
  }
}

// ---------------------------------------------------------------------------
// Kernel 4: out = y[B*T,128] @ Wproj[128,1024]  (fp32).
// ---------------------------------------------------------------------------
__global__ __launch_bounds__(256) void out_proj(
    const float* __restrict__ y, const float* __restrict__ Wproj,
    float* __restrict__ out) {
  __shared__ float ylds[4][128];
  const int m0 = blockIdx.x * 4;
  const int tid = threadIdx.x;
  *(float2*)&((float*)ylds)[tid * 2] = *(const float2*)&y[(size_t)m0 * 128 + tid * 2];
  __syncthreads();
  float acc[4][4];
#pragma unroll
  for (int i = 0; i < 4; i++)
#pragma unroll
    for (int j = 0; j < 4; j++) acc[i][j] = 0.0f;
  for (int k = 0; k < 128; k++) {
    float w[4];
#pragma unroll
    for (int j = 0; j < 4; j++) w[j] = Wproj[(size_t)k * 1024 + tid + 256 * j];
#pragma unroll
    for (int i = 0; i < 4; i++) {
      float yv = ylds[i][k];
#pragma unroll
      for (int j = 0; j < 4; j++) acc[i][j] += yv * w[j];
    }
  }
#pragma unroll
  for (int i = 0; i < 4; i++)
#pragma unroll
    for (int j = 0; j < 4; j++)
      out[(size_t)(m0 + i) * 1024 + tid + 256 * j] = acc[i][j];
}

// ---------------------------------------------------------------------------
extern "C" void kernel_launch(void* const* d_in, const int* in_sizes, int n_in,
                              void* d_out, int out_size, void* d_ws, size_t ws_size,
                              hipStream_t stream) {
  const float* x     = (const float*)d_in[0];
  const float* Wq    = (const float*)d_in[2];
  const float* Wk    = (const float*)d_in[3];
  const float* Wv    = (const float*)d_in[4];
  const float* Wproj = (const float*)d_in[5];
  const float* lobo  = (const float*)d_in[6];
  const float* qknf  = (const float*)d_in[7];
  float* out = (float*)d_out;

  // ws: [qkv0 f32 29.4MB | qkv1c bf16 14.7MB | xb bf16 16.8MB | wt bf16 7.3MB]
  // qf/kf/vf/y alias xb exactly (dead after gemm). Total 68.2 MB.
  float* qkv0 = (float*)d_ws;                                   // 7,340,032 f32
  ushort_t* qkv1c = (ushort_t*)(qkv0 + (size_t)B_ * T_ * NQKV); // 7,340,032 bf16
  ushort_t* xb = qkv1c + (size_t)B_ * T_ * NQKV;                // 8,388,608 bf16
  ushort_t* wt = xb + (size_t)B_ * T_ * KS2;                    // 3,670,016 bf16
  ushort_t* qf = xb;                                            // 4,194,304 bf16
  ushort_t* kf = qf + (size_t)B_ * H_ * T_ * 64;                // 1,048,576 bf16
  ushort_t* vf = kf + (size_t)B_ * G_ * T_ * 64;                // 2,097,152 bf16
  float* y = (float*)(vf + (size_t)B_ * G_ * T_ * 128);         //   524,288 f32

  cast_x<<<(B_ * T_ * C_ / 4) / 256, 256, 0, stream>>>(x, xb);
  dim3 gw(NQKV / 64, C_ / 64);
  cast_w<<<gw, 256, 0, stream>>>(Wq, Wk, Wv, wt);

  dim3 gg(NQKV / 128, (B_ * T_) / 128, 2);
  gemm_qkv_mfma<<<gg, 256, 0, stream>>>(xb, wt, qkv0, qkv1c);

  int nvec = B_ * T_ * H_ + B_ * T_ * G_;   // 81920
  rope_norm<<<nvec / 4, 256, 0, stream>>>(qkv0, qkv1c, qf, kf);

  vscatter<<<(B_ * G_ * T_ * DV_) / 256, 256, 0, stream>>>(qkv0, qkv1c, vf);

  (void)hipMemsetAsync(y, 0, (size_t)B_ * T_ * 128 * sizeof(float), stream);

  attn<<<B_ * H_ * (T_ / 64), 256, 0, stream>>>(qf, kf, vf, lobo, qknf, y);

  out_proj<<<(B_ * T_) / 4, 256, 0, stream>>>(y, Wproj, out);
}